// Round 3
// baseline (433.209 us; speedup 1.0000x reference)
//
#include <hip/hip_runtime.h>
#include <math.h>

// ---------------------------------------------------------------------------
// MultiheadAttention B=2,S=2048,D=1024,H=16,HD=64. I/O fp32; internal fp16 MFMA.
//   0) cvt: q,k,v,WQ..WO fp32 -> fp16 (once)
//   1) QKV gemm (m97-style: global_load_lds 16B, unpadded LDS 128x64)
//      -> Q,K fp16 [B,H,S,64]; V fp16 transposed [B,H,64,S]
//   2) flash attention: 64 q-rows/block, 128-key tiles, mask via LDS fp16,
//      P aliases per-wave mask rows -> AO fp16 [B,S,1024]
//   3) O projection -> d_out fp32
// ---------------------------------------------------------------------------

typedef _Float16 h8 __attribute__((ext_vector_type(8)));
typedef _Float16 h4 __attribute__((ext_vector_type(4)));
typedef float f4 __attribute__((ext_vector_type(4)));

#define MFMA16(a, b, c) __builtin_amdgcn_mfma_f32_16x16x32_f16((a), (b), (c), 0, 0, 0)

static constexpr int Bn = 2, Sn = 2048, Dn = 1024, Hn = 16, HDn = 64;
static constexpr int Mn = Bn * Sn;   // 4096
static constexpr int Kn = Dn;        // 1024
static constexpr int Nn = Dn;        // 1024
static constexpr int LDA = 72;       // attn K-tile LDS stride (halfs)
static constexpr int LDB = 136;      // attn V/mask/P LDS stride (halfs)

__device__ __forceinline__ void gload_lds16(const _Float16* g, _Float16* l) {
  // LDS dest is wave-uniform base; HW scatters lane i -> base + i*16 [m104]
  __builtin_amdgcn_global_load_lds(
      (const __attribute__((address_space(1))) unsigned int*)g,
      (__attribute__((address_space(3))) unsigned int*)l, 16, 0, 0);
}

// ------------------------------- cvt pass ----------------------------------
struct CvtJobs {
  const float* src[7];
  _Float16* dst[7];
  int n4[7];  // count of float4 chunks
};

__global__ __launch_bounds__(256) void cvt_kernel(CvtJobs j) {
  const int stride = gridDim.x * blockDim.x;
  const int t0 = blockIdx.x * blockDim.x + threadIdx.x;
#pragma unroll
  for (int k = 0; k < 7; ++k) {
    const float4* __restrict__ s = (const float4*)j.src[k];
    h4* __restrict__ d = (h4*)j.dst[k];
    const int n = j.n4[k];
    for (int i = t0; i < n; i += stride) {
      const float4 f = s[i];
      h4 h;
      h[0] = (_Float16)f.x; h[1] = (_Float16)f.y;
      h[2] = (_Float16)f.z; h[3] = (_Float16)f.w;
      d[i] = h;
    }
  }
}

// ------------------------------- GEMM --------------------------------------
struct GemmArgs {
  const _Float16* X[3];
  const _Float16* W[3];
  const float* bias[3];
  void* out[3];   // mode 0: float*, modes 1/2: _Float16*
  int mode[3];    // 0 plain fp32 [M,N]; 1 fp16 [B,H,S,64]; 2 fp16 [B,H,64,S]
};

// C = X @ W^T + bias. 128x128 tile, BK=64, 4 waves 2x2, m97-style staging.
__global__ __launch_bounds__(256) void gemm_f16(GemmArgs args) {
  const int z = blockIdx.z;
  const _Float16* __restrict__ X = args.X[z];
  const _Float16* __restrict__ W = args.W[z];
  const float* __restrict__ bias = args.bias[z];
  const int mode = args.mode[z];

  __shared__ _Float16 As[128 * 64];   // unpadded: required by global_load_lds
  __shared__ _Float16 Bs[128 * 64];

  const int t = threadIdx.x;
  const int lane = t & 63, wv = t >> 6;
  const int l15 = lane & 15, quad = lane >> 4;
  const int wm = (wv >> 1) * 64, wn = (wv & 1) * 64;
  const int n0 = blockIdx.x * 128, m0 = blockIdx.y * 128;

  f4 acc[4][4];
#pragma unroll
  for (int i = 0; i < 4; ++i)
#pragma unroll
    for (int j = 0; j < 4; ++j) {
      f4 zz = {0.f, 0.f, 0.f, 0.f};
      acc[i][j] = zz;
    }

  // staging geometry: chunk c = slab*64 + lane; row = c>>3, col8 = c&7
  const int srow = lane >> 3, scol = (lane & 7) * 8;

  for (int k0 = 0; k0 < Kn; k0 += 64) {
    __syncthreads();
#pragma unroll
    for (int u = 0; u < 4; ++u) {
      const int s = wv * 4 + u;          // wave-uniform slab id
      const int row = s * 8 + srow;
      gload_lds16(X + (size_t)(m0 + row) * Kn + k0 + scol, &As[s * 512]);
      gload_lds16(W + (size_t)(n0 + row) * Kn + k0 + scol, &Bs[s * 512]);
    }
    __syncthreads();
#pragma unroll
    for (int kk = 0; kk < 64; kk += 32) {
      h8 af[4], bfr[4];
#pragma unroll
      for (int i = 0; i < 4; ++i)
        af[i] = *(const h8*)&As[(wm + i * 16 + l15) * 64 + kk + quad * 8];
#pragma unroll
      for (int j = 0; j < 4; ++j)
        bfr[j] = *(const h8*)&Bs[(wn + j * 16 + l15) * 64 + kk + quad * 8];
#pragma unroll
      for (int i = 0; i < 4; ++i)
#pragma unroll
        for (int j = 0; j < 4; ++j)
          acc[i][j] = MFMA16(af[i], bfr[j], acc[i][j]);
    }
  }

  // Epilogue: C/D layout col = lane&15, row = quad*4 + r [m89/m91]
#pragma unroll
  for (int j = 0; j < 4; ++j) {
    const int n = n0 + wn + j * 16 + l15;
    const float bv = bias[n];
    const int hh = n >> 6, hd = n & 63;
#pragma unroll
    for (int i = 0; i < 4; ++i) {
      const int mb = m0 + wm + i * 16 + quad * 4;
      if (mode == 2) {
        const int bb = mb >> 11, ss = mb & (Sn - 1);
        h4 hv;
#pragma unroll
        for (int r = 0; r < 4; ++r) hv[r] = (_Float16)(acc[i][j][r] + bv);
        *(h4*)((_Float16*)args.out[z] +
               (((size_t)(bb * Hn + hh)) * HDn + hd) * Sn + ss) = hv;
      } else {
#pragma unroll
        for (int r = 0; r < 4; ++r) {
          const int m = mb + r;
          const float fv = acc[i][j][r] + bv;
          if (mode == 0) {
            ((float*)args.out[z])[(size_t)m * Nn + n] = fv;
          } else {
            const int bb = m >> 11, ss = m & (Sn - 1);
            ((_Float16*)args.out[z])
                [(((size_t)(bb * Hn + hh)) * Sn + ss) * HDn + hd] = (_Float16)fv;
          }
        }
      }
    }
  }
}

// ------------------------------ attention ----------------------------------
// Block = 4 waves; wave w owns q rows [q0, q0+16). 128-key tiles.
__global__ __launch_bounds__(256) void attn_kernel(
    const _Float16* __restrict__ Qh,   // [B,H,S,64]
    const _Float16* __restrict__ Kh,   // [B,H,S,64]
    const _Float16* __restrict__ Vt,   // [B,H,64,S]
    const float* __restrict__ mask,    // [B,S,S] fp32
    _Float16* __restrict__ out) {      // [B,S,1024] fp16
  __shared__ _Float16 Kl[128 * LDA];
  __shared__ _Float16 Vl[64 * LDB];
  __shared__ _Float16 Ml[64 * LDB];   // mask tile; wave w's rows [16w,16w+16) reused as P

  const int t = threadIdx.x;
  const int w = t >> 6, lane = t & 63;
  const int l15 = lane & 15, quad = lane >> 4;

  const int bh = blockIdx.y;
  const int b = bh >> 4, h = bh & 15;
  const size_t headoff = (size_t)bh * Sn * HDn;
  const _Float16* Qp = Qh + headoff;
  const _Float16* Kp = Kh + headoff;
  const _Float16* Vp = Vt + headoff;

  const int qb = blockIdx.x * 64;
  const int q0 = qb + w * 16;
  const h8 qf0 = *(const h8*)(Qp + (size_t)(q0 + l15) * HDn + quad * 8);
  const h8 qf1 = *(const h8*)(Qp + (size_t)(q0 + l15) * HDn + 32 + quad * 8);

  const float* mbase = mask + ((size_t)b * Sn + qb) * Sn;

  float m_r[4], l_r[4];
  f4 o_acc[4];
#pragma unroll
  for (int r = 0; r < 4; ++r) { m_r[r] = -INFINITY; l_r[r] = 0.f; }
#pragma unroll
  for (int nt = 0; nt < 4; ++nt) {
    f4 zz = {0.f, 0.f, 0.f, 0.f};
    o_acc[nt] = zz;
  }

  _Float16* Pw = &Ml[(w * 16) * LDB];  // alias: this wave's 16 mask rows
  const int mrow = t >> 2, mcol0 = (t & 3) * 32;  // mask staging map

  for (int kt = 0; kt < Sn / 128; ++kt) {
    __syncthreads();  // prior iteration's Vl/Ml(P) reads complete
    // ---- stage K tile [128 keys][64 dims] ----
#pragma unroll
    for (int u = 0; u < 4; ++u) {
      const int c = t + u * 256;
      const int row = c >> 3, c8 = (c & 7) * 8;
      *(uint4*)&Kl[row * LDA + c8] =
          *(const uint4*)(Kp + (size_t)(kt * 128 + row) * HDn + c8);
    }
    // ---- stage V tile [64 dims][128 keys] (already transposed in global) ----
#pragma unroll
    for (int u = 0; u < 4; ++u) {
      const int c = t + u * 256;
      const int row = c >> 4, c8 = (c & 15) * 8;
      *(uint4*)&Vl[row * LDB + c8] =
          *(const uint4*)(Vp + (size_t)row * Sn + kt * 128 + c8);
    }
    // ---- stage mask tile [64 q][128 k] fp32 -> fp16 ----
#pragma unroll
    for (int u = 0; u < 4; ++u) {
      const float4 f0 = *(const float4*)(mbase + (size_t)mrow * Sn + kt * 128 + mcol0 + u * 8);
      const float4 f1 = *(const float4*)(mbase + (size_t)mrow * Sn + kt * 128 + mcol0 + u * 8 + 4);
      h8 hm;
      hm[0] = (_Float16)f0.x; hm[1] = (_Float16)f0.y; hm[2] = (_Float16)f0.z; hm[3] = (_Float16)f0.w;
      hm[4] = (_Float16)f1.x; hm[5] = (_Float16)f1.y; hm[6] = (_Float16)f1.z; hm[7] = (_Float16)f1.w;
      *(h8*)&Ml[mrow * LDB + mcol0 + u * 8] = hm;
    }
    __syncthreads();

    // ---- QK^T: 8 subtiles of 16 keys ----
    f4 s[8];
#pragma unroll
    for (int ks = 0; ks < 8; ++ks) {
      const h8 kf0 = *(const h8*)&Kl[(ks * 16 + l15) * LDA + quad * 8];
      const h8 kf1 = *(const h8*)&Kl[(ks * 16 + l15) * LDA + 32 + quad * 8];
      f4 a = {0.f, 0.f, 0.f, 0.f};
      a = MFMA16(qf0, kf0, a);
      a = MFMA16(qf1, kf1, a);
#pragma unroll
      for (int r = 0; r < 4; ++r)
        s[ks][r] = a[r] * 0.125f +
                   (float)Ml[(w * 16 + quad * 4 + r) * LDB + ks * 16 + l15];
    }

    // ---- online softmax over the 128-key tile ----
    float nm[4], alpha[4];
#pragma unroll
    for (int r = 0; r < 4; ++r) {
      float mx = s[0][r];
#pragma unroll
      for (int ks = 1; ks < 8; ++ks) mx = fmaxf(mx, s[ks][r]);
#pragma unroll
      for (int off = 1; off < 16; off <<= 1) mx = fmaxf(mx, __shfl_xor(mx, off));
      nm[r] = fmaxf(m_r[r], mx);
      alpha[r] = __expf(m_r[r] - nm[r]);
      m_r[r] = nm[r];
    }
#pragma unroll
    for (int ks = 0; ks < 8; ++ks)
#pragma unroll
      for (int r = 0; r < 4; ++r) s[ks][r] = __expf(s[ks][r] - nm[r]);
#pragma unroll
    for (int r = 0; r < 4; ++r) {
      float sm = 0.f;
#pragma unroll
      for (int ks = 0; ks < 8; ++ks) sm += s[ks][r];
#pragma unroll
      for (int off = 1; off < 16; off <<= 1) sm += __shfl_xor(sm, off);
      l_r[r] = l_r[r] * alpha[r] + sm;
    }
#pragma unroll
    for (int nt = 0; nt < 4; ++nt)
#pragma unroll
      for (int r = 0; r < 4; ++r) o_acc[nt][r] *= alpha[r];

    // ---- P (C-layout) -> per-wave LDS slab (aliases consumed mask rows) ----
#pragma unroll
    for (int ks = 0; ks < 8; ++ks)
#pragma unroll
      for (int r = 0; r < 4; ++r)
        Pw[(quad * 4 + r) * LDB + ks * 16 + l15] = (_Float16)s[ks][r];
    // no barrier: Pw is wave-private; DS pipe is in-order within a wave

    // ---- PV: O[16q x 64d] += P[16 x 128] @ V[128 x 64d] ----
#pragma unroll
    for (int kk = 0; kk < 128; kk += 32) {
      const h8 pf = *(const h8*)&Pw[l15 * LDB + kk + quad * 8];
#pragma unroll
      for (int nt = 0; nt < 4; ++nt) {
        const h8 vf = *(const h8*)&Vl[(nt * 16 + l15) * LDB + kk + quad * 8];
        o_acc[nt] = MFMA16(pf, vf, o_acc[nt]);
      }
    }
  }

  // epilogue -> AO fp16 [B,S,1024]
#pragma unroll
  for (int nt = 0; nt < 4; ++nt) {
#pragma unroll
    for (int r = 0; r < 4; ++r) {
      const int qg = q0 + quad * 4 + r;
      const int col = h * 64 + nt * 16 + l15;
      out[((size_t)b * Sn + qg) * Dn + col] = (_Float16)(o_acc[nt][r] / l_r[r]);
    }
  }
}

// ------------------------------ launch -------------------------------------
extern "C" void kernel_launch(void* const* d_in, const int* in_sizes, int n_in,
                              void* d_out, int out_size, void* d_ws, size_t ws_size,
                              hipStream_t stream) {
  const float* q = (const float*)d_in[0];
  const float* k = (const float*)d_in[1];
  const float* v = (const float*)d_in[2];
  const float* mask = (const float*)d_in[3];
  const float* WQ = (const float*)d_in[4];
  const float* bQ = (const float*)d_in[5];
  const float* WK = (const float*)d_in[6];
  const float* bK = (const float*)d_in[7];
  const float* WV = (const float*)d_in[8];
  const float* bV = (const float*)d_in[9];
  const float* WO = (const float*)d_in[10];
  const float* bO = (const float*)d_in[11];

  _Float16* ws = (_Float16*)d_ws;
  const size_t MD = (size_t)Mn * Dn;        // 4.19M elements
  const size_t DD = (size_t)Dn * Dn;        // 1.05M
  _Float16* qh  = ws;                       // fp16 inputs
  _Float16* kh  = ws + MD;
  _Float16* vh  = ws + 2 * MD;
  _Float16* WQh = ws + 3 * MD;
  _Float16* WKh = WQh + DD;
  _Float16* WVh = WKh + DD;
  _Float16* WOh = WVh + DD;
  _Float16* Qh  = ws + 3 * MD + 4 * DD;     // head-split
  _Float16* Kh  = Qh + MD;
  _Float16* Vt  = Kh + MD;
  _Float16* AO  = qh;                        // reuse (qh dead after QKV gemm)

  CvtJobs cj;
  cj.src[0] = q;  cj.dst[0] = qh;  cj.n4[0] = (int)(MD / 4);
  cj.src[1] = k;  cj.dst[1] = kh;  cj.n4[1] = (int)(MD / 4);
  cj.src[2] = v;  cj.dst[2] = vh;  cj.n4[2] = (int)(MD / 4);
  cj.src[3] = WQ; cj.dst[3] = WQh; cj.n4[3] = (int)(DD / 4);
  cj.src[4] = WK; cj.dst[4] = WKh; cj.n4[4] = (int)(DD / 4);
  cj.src[5] = WV; cj.dst[5] = WVh; cj.n4[5] = (int)(DD / 4);
  cj.src[6] = WO; cj.dst[6] = WOh; cj.n4[6] = (int)(DD / 4);
  cvt_kernel<<<1024, 256, 0, stream>>>(cj);

  GemmArgs ga;
  ga.X[0] = qh; ga.W[0] = WQh; ga.bias[0] = bQ; ga.out[0] = Qh; ga.mode[0] = 1;
  ga.X[1] = kh; ga.W[1] = WKh; ga.bias[1] = bK; ga.out[1] = Kh; ga.mode[1] = 1;
  ga.X[2] = vh; ga.W[2] = WVh; ga.bias[2] = bV; ga.out[2] = Vt; ga.mode[2] = 2;
  gemm_f16<<<dim3(Nn / 128, Mn / 128, 3), 256, 0, stream>>>(ga);

  attn_kernel<<<dim3(Sn / 64, Bn * Hn), 256, 0, stream>>>(Qh, Kh, Vt, mask, AO);

  GemmArgs go;
  for (int i = 0; i < 3; ++i) {
    go.X[i] = AO; go.W[i] = WOh; go.bias[i] = bO;
    go.out[i] = d_out; go.mode[i] = 0;
  }
  gemm_f16<<<dim3(Nn / 128, Mn / 128, 1), 256, 0, stream>>>(go);
}

// Round 4
// 300.315 us; speedup vs baseline: 1.4425x; 1.4425x over previous
//
#include <hip/hip_runtime.h>
#include <math.h>

// ---------------------------------------------------------------------------
// MultiheadAttention B=2,S=2048,D=1024,H=16,HD=64. I/O fp32; internal fp16 MFMA.
//   0) cvt: q,k,v,WQ..WO fp32 -> fp16 (once)
//   1) gemm_qkv (m97 staging): Q fp16 [B,H,S,64] (pre-scaled by 1/8),
//      K fp16 [B,H,S,64], V fp16 transposed [B,H,64,S]; LDS-transpose epilogues
//   2) attn: TRANSPOSED scores S^T = K Q^T  (C col = q) -> per-lane scalar
//      online softmax, packed P^T, PV^T, wave-private O transpose -> AO fp16
//   3) gemm_o: AO @ WO^T + b -> d_out fp32
// ---------------------------------------------------------------------------

typedef _Float16 h8 __attribute__((ext_vector_type(8)));
typedef _Float16 h4 __attribute__((ext_vector_type(4)));
typedef float f4 __attribute__((ext_vector_type(4)));

#define MFMA16(a, b, c) __builtin_amdgcn_mfma_f32_16x16x32_f16((a), (b), (c), 0, 0, 0)

static constexpr int Bn = 2, Sn = 2048, Dn = 1024, Hn = 16, HDn = 64;
static constexpr int Mn = Bn * Sn;   // 4096
static constexpr int Kn = Dn;        // 1024
static constexpr int Nn = Dn;        // 1024
static constexpr int LDA = 72;       // attn LDS stride (64 + 8 pad)
static constexpr int LDC = 136;      // gemm epilogue LDS stride (128 + 8 pad)

__device__ __forceinline__ void gload_lds16(const _Float16* g, _Float16* l) {
  // wave-uniform LDS base; HW scatters lane i -> base + i*16 bytes [m104]
  __builtin_amdgcn_global_load_lds(
      (const __attribute__((address_space(1))) unsigned int*)g,
      (__attribute__((address_space(3))) unsigned int*)l, 16, 0, 0);
}

// ------------------------------- cvt pass ----------------------------------
struct CvtJobs {
  const float* src[7];
  _Float16* dst[7];
  int n4[7];
};

__global__ __launch_bounds__(256) void cvt_kernel(CvtJobs j) {
  const int stride = gridDim.x * blockDim.x;
  const int t0 = blockIdx.x * blockDim.x + threadIdx.x;
#pragma unroll
  for (int k = 0; k < 7; ++k) {
    const float4* __restrict__ s = (const float4*)j.src[k];
    h4* __restrict__ d = (h4*)j.dst[k];
    const int n = j.n4[k];
    for (int i = t0; i < n; i += stride) {
      const float4 f = s[i];
      h4 h;
      h[0] = (_Float16)f.x; h[1] = (_Float16)f.y;
      h[2] = (_Float16)f.z; h[3] = (_Float16)f.w;
      d[i] = h;
    }
  }
}

// ------------------------------- QKV GEMM ----------------------------------
struct QkvArgs {
  const _Float16* X[3];
  const _Float16* W[3];
  const float* bias[3];
  _Float16* out[3];
};

// C = X @ W^T + bias. 128x128 tile, BK=64, 4 waves 2x2, m97-style staging.
// z=0: Q (scaled 1/8) -> [B,H,S,64]; z=1: K -> [B,H,S,64]; z=2: V -> [B,H,64,S]
__global__ __launch_bounds__(256) void gemm_qkv(QkvArgs args) {
  const int z = blockIdx.z;
  const _Float16* __restrict__ X = args.X[z];
  const _Float16* __restrict__ W = args.W[z];
  const float* __restrict__ bias = args.bias[z];
  _Float16* __restrict__ out = args.out[z];
  const float oscale = (z == 0) ? 0.125f : 1.0f;

  __shared__ _Float16 smem[128 * LDC];  // 34816 B; staging aliases first 32 KB
  _Float16* As = smem;
  _Float16* Bs = smem + 128 * 64;

  const int t = threadIdx.x;
  const int lane = t & 63, wv = t >> 6;
  const int l15 = lane & 15, quad = lane >> 4;
  const int wm = (wv >> 1) * 64, wn = (wv & 1) * 64;
  const int n0 = blockIdx.x * 128, m0 = blockIdx.y * 128;

  f4 acc[4][4];
#pragma unroll
  for (int i = 0; i < 4; ++i)
#pragma unroll
    for (int j = 0; j < 4; ++j) {
      f4 zz = {0.f, 0.f, 0.f, 0.f};
      acc[i][j] = zz;
    }

  const int srow = lane >> 3, scol = (lane & 7) * 8;

  for (int k0 = 0; k0 < Kn; k0 += 64) {
    __syncthreads();
#pragma unroll
    for (int u = 0; u < 4; ++u) {
      const int s = wv * 4 + u;
      const int row = s * 8 + srow;
      gload_lds16(X + (size_t)(m0 + row) * Kn + k0 + scol, As + s * 512);
      gload_lds16(W + (size_t)(n0 + row) * Kn + k0 + scol, Bs + s * 512);
    }
    __syncthreads();
#pragma unroll
    for (int kk = 0; kk < 64; kk += 32) {
      h8 af[4], bfr[4];
#pragma unroll
      for (int i = 0; i < 4; ++i)
        af[i] = *(const h8*)&As[(wm + i * 16 + l15) * 64 + kk + quad * 8];
#pragma unroll
      for (int j = 0; j < 4; ++j)
        bfr[j] = *(const h8*)&Bs[(wn + j * 16 + l15) * 64 + kk + quad * 8];
#pragma unroll
      for (int i = 0; i < 4; ++i)
#pragma unroll
        for (int j = 0; j < 4; ++j)
          acc[i][j] = MFMA16(af[i], bfr[j], acc[i][j]);
    }
  }

  // ---- epilogue via LDS transpose, coalesced uint4 stores ----
  __syncthreads();  // K-loop LDS reads done; reuse smem
  if (z != 2) {
    // Cm[m][n] (stride LDC): frag writes scalar, readback row-major
#pragma unroll
    for (int j = 0; j < 4; ++j) {
      const float bv = bias[n0 + wn + j * 16 + l15] * oscale;
#pragma unroll
      for (int i = 0; i < 4; ++i)
#pragma unroll
        for (int r = 0; r < 4; ++r)
          smem[(wm + i * 16 + quad * 4 + r) * LDC + wn + j * 16 + l15] =
              (_Float16)(acc[i][j][r] * oscale + bv);
    }
    __syncthreads();
    const int ml = t >> 1, seg = (t & 1) * 64;
    const int m = m0 + ml;
    const int bb = m >> 11, ss = m & (Sn - 1);
#pragma unroll
    for (int u = 0; u < 8; ++u) {
      const int n = n0 + seg + u * 8;
      const int hh = n >> 6, hd = n & 63;
      *(uint4*)(out + (((size_t)(bb * Hn + hh)) * Sn + ss) * HDn + hd) =
          *(const uint4*)&smem[ml * LDC + seg + u * 8];
    }
  } else {
    // Ct[n][m] (stride LDC): frag writes h4 (b64), readback -> Vt[d][token]
#pragma unroll
    for (int j = 0; j < 4; ++j) {
      const float bv = bias[n0 + wn + j * 16 + l15];
#pragma unroll
      for (int i = 0; i < 4; ++i) {
        h4 hv;
#pragma unroll
        for (int r = 0; r < 4; ++r) hv[r] = (_Float16)(acc[i][j][r] + bv);
        *(h4*)&smem[(wn + j * 16 + l15) * LDC + wm + i * 16 + quad * 4] = hv;
      }
    }
    __syncthreads();
    const int nl = t >> 1, seg = (t & 1) * 64;
    const int n = n0 + nl;
    const int hh = n >> 6, hd = n & 63;
    const int bb = (m0 + seg) >> 11;
#pragma unroll
    for (int u = 0; u < 8; ++u) {
      const int ss = (m0 + seg + u * 8) & (Sn - 1);
      *(uint4*)(out + (((size_t)(bb * Hn + hh)) * HDn + hd) * Sn + ss) =
          *(const uint4*)&smem[nl * LDC + seg + u * 8];
    }
  }
}

// ------------------------------- O GEMM ------------------------------------
__global__ __launch_bounds__(256) void gemm_o(const _Float16* __restrict__ X,
                                              const _Float16* __restrict__ W,
                                              const float* __restrict__ bias,
                                              float* __restrict__ out) {
  __shared__ _Float16 As[128 * 64];
  __shared__ _Float16 Bs[128 * 64];

  const int t = threadIdx.x;
  const int lane = t & 63, wv = t >> 6;
  const int l15 = lane & 15, quad = lane >> 4;
  const int wm = (wv >> 1) * 64, wn = (wv & 1) * 64;
  const int n0 = blockIdx.x * 128, m0 = blockIdx.y * 128;

  f4 acc[4][4];
#pragma unroll
  for (int i = 0; i < 4; ++i)
#pragma unroll
    for (int j = 0; j < 4; ++j) {
      f4 zz = {0.f, 0.f, 0.f, 0.f};
      acc[i][j] = zz;
    }

  const int srow = lane >> 3, scol = (lane & 7) * 8;

  for (int k0 = 0; k0 < Kn; k0 += 64) {
    __syncthreads();
#pragma unroll
    for (int u = 0; u < 4; ++u) {
      const int s = wv * 4 + u;
      const int row = s * 8 + srow;
      gload_lds16(X + (size_t)(m0 + row) * Kn + k0 + scol, As + s * 512);
      gload_lds16(W + (size_t)(n0 + row) * Kn + k0 + scol, Bs + s * 512);
    }
    __syncthreads();
#pragma unroll
    for (int kk = 0; kk < 64; kk += 32) {
      h8 af[4], bfr[4];
#pragma unroll
      for (int i = 0; i < 4; ++i)
        af[i] = *(const h8*)&As[(wm + i * 16 + l15) * 64 + kk + quad * 8];
#pragma unroll
      for (int j = 0; j < 4; ++j)
        bfr[j] = *(const h8*)&Bs[(wn + j * 16 + l15) * 64 + kk + quad * 8];
#pragma unroll
      for (int i = 0; i < 4; ++i)
#pragma unroll
        for (int j = 0; j < 4; ++j)
          acc[i][j] = MFMA16(af[i], bfr[j], acc[i][j]);
    }
  }

  // m97-proven direct fp32 stores
#pragma unroll
  for (int j = 0; j < 4; ++j) {
    const int n = n0 + wn + j * 16 + l15;
    const float bv = bias[n];
#pragma unroll
    for (int i = 0; i < 4; ++i) {
      const int mb = m0 + wm + i * 16 + quad * 4;
#pragma unroll
      for (int r = 0; r < 4; ++r)
        out[(size_t)(mb + r) * Nn + n] = acc[i][j][r] + bv;
    }
  }
}

// ------------------------------ attention ----------------------------------
// Transposed scores: S^T = K Q^T, C col = l15 = q. Block = 4 waves x 16 q.
__global__ __launch_bounds__(256) void attn_kernel(
    const _Float16* __restrict__ Qh,   // [B,H,S,64], pre-scaled by 1/8
    const _Float16* __restrict__ Kh,   // [B,H,S,64]
    const _Float16* __restrict__ Vt,   // [B,H,64,S]
    const float* __restrict__ mask,    // [B,S,S] fp32
    _Float16* __restrict__ out) {      // [B,S,1024] fp16
  __shared__ _Float16 Kl[64 * LDA];
  __shared__ _Float16 Vl[64 * LDA];
  __shared__ _Float16 Pl[4 * 16 * LDA];  // per-wave P^T / O-transpose slab

  const int t = threadIdx.x;
  const int w = t >> 6, lane = t & 63;
  const int l15 = lane & 15, quad = lane >> 4;

  const int bh = blockIdx.y;
  const int b = bh >> 4, h = bh & 15;
  const size_t headoff = (size_t)bh * Sn * HDn;
  const _Float16* Qp = Qh + headoff;
  const _Float16* Kp = Kh + headoff;
  const _Float16* Vp = Vt + headoff;

  const int qb = blockIdx.x * 64;
  const int q0 = qb + w * 16;
  // Q as B-operand: n = l15 -> q, k = quad*8+j -> d
  const h8 qf0 = *(const h8*)(Qp + (size_t)(q0 + l15) * HDn + quad * 8);
  const h8 qf1 = *(const h8*)(Qp + (size_t)(q0 + l15) * HDn + 32 + quad * 8);

  const float* mrow = mask + ((size_t)b * Sn + q0 + l15) * Sn;  // per-lane q row

  float m_run = -INFINITY, l_run = 0.f;
  f4 o_acc[4];
#pragma unroll
  for (int nt = 0; nt < 4; ++nt) {
    f4 zz = {0.f, 0.f, 0.f, 0.f};
    o_acc[nt] = zz;
  }

  _Float16* Pw = &Pl[(w * 16) * LDA];

  for (int kt = 0; kt < Sn / 64; ++kt) {
    __syncthreads();  // prior iteration's Kl/Vl reads complete
#pragma unroll
    for (int u = 0; u < 2; ++u) {
      const int c = t + u * 256;
      const int row = c >> 3, c8 = (c & 7) * 8;
      *(uint4*)&Kl[row * LDA + c8] =
          *(const uint4*)(Kp + (size_t)(kt * 64 + row) * HDn + c8);
      *(uint4*)&Vl[row * LDA + c8] =
          *(const uint4*)(Vp + (size_t)row * Sn + kt * 64 + c8);
    }
    __syncthreads();

    // ---- S^T = K Q^T: rows = keys (quad*4+r), cols = q (l15) ----
    f4 s[4];
#pragma unroll
    for (int ks = 0; ks < 4; ++ks) {
      const h8 kf0 = *(const h8*)&Kl[(ks * 16 + l15) * LDA + quad * 8];
      const h8 kf1 = *(const h8*)&Kl[(ks * 16 + l15) * LDA + 32 + quad * 8];
      f4 a = {0.f, 0.f, 0.f, 0.f};
      a = MFMA16(kf0, qf0, a);
      a = MFMA16(kf1, qf1, a);
      const float4 mv = *(const float4*)(mrow + kt * 64 + ks * 16 + quad * 4);
#pragma unroll
      for (int r = 0; r < 4; ++r) s[ks][r] = a[r] + ((const float*)&mv)[r];
    }

    // ---- per-lane scalar online softmax (lane's q = l15) ----
    float mx = s[0][0];
#pragma unroll
    for (int ks = 0; ks < 4; ++ks)
#pragma unroll
      for (int r = 0; r < 4; ++r) mx = fmaxf(mx, s[ks][r]);
    mx = fmaxf(mx, __shfl_xor(mx, 16));
    mx = fmaxf(mx, __shfl_xor(mx, 32));
    const float nm = fmaxf(m_run, mx);
    const float alpha = __expf(m_run - nm);
    m_run = nm;
    float sm = 0.f;
#pragma unroll
    for (int ks = 0; ks < 4; ++ks)
#pragma unroll
      for (int r = 0; r < 4; ++r) {
        s[ks][r] = __expf(s[ks][r] - nm);
        sm += s[ks][r];
      }
    sm += __shfl_xor(sm, 16);
    sm += __shfl_xor(sm, 32);
    l_run = l_run * alpha + sm;
#pragma unroll
    for (int nt = 0; nt < 4; ++nt)
#pragma unroll
      for (int r = 0; r < 4; ++r) o_acc[nt][r] *= alpha;

    // ---- P^T packed write: Pw[q=l15][key], b64 stores ----
#pragma unroll
    for (int ks = 0; ks < 4; ++ks) {
      h4 pv;
#pragma unroll
      for (int r = 0; r < 4; ++r) pv[r] = (_Float16)s[ks][r];
      *(h4*)&Pw[l15 * LDA + ks * 16 + quad * 4] = pv;
    }
    // (wave-private slab; in-wave DS ordering validated R3 — no barrier)

    // ---- O^T += V^T P^T: A = V^T[d][key], B = P^T (b128 reads) ----
#pragma unroll
    for (int kk = 0; kk < 64; kk += 32) {
      const h8 pf = *(const h8*)&Pw[l15 * LDA + kk + quad * 8];
#pragma unroll
      for (int nt = 0; nt < 4; ++nt) {
        const h8 vf = *(const h8*)&Vl[(nt * 16 + l15) * LDA + kk + quad * 8];
        o_acc[nt] = MFMA16(vf, pf, o_acc[nt]);
      }
    }
  }

  // ---- epilogue: O^T -> wave-private LDS transpose -> coalesced stores ----
  const float rl = 1.0f / l_run;
#pragma unroll
  for (int nt = 0; nt < 4; ++nt) {
    h4 ov;
#pragma unroll
    for (int r = 0; r < 4; ++r) ov[r] = (_Float16)(o_acc[nt][r] * rl);
    *(h4*)&Pw[l15 * LDA + nt * 16 + quad * 4] = ov;  // Ob[q_local][d]
  }
  const int qr = lane >> 2;            // 0..15
  const int seg = (lane & 3) * 16;     // 0,16,32,48
  const int qg = q0 + qr;
  _Float16* dst = out + ((size_t)b * Sn + qg) * Dn + h * 64 + seg;
  *(uint4*)dst = *(const uint4*)&Pw[qr * LDA + seg];
  *(uint4*)(dst + 8) = *(const uint4*)&Pw[qr * LDA + seg + 8];
}

// ------------------------------ launch -------------------------------------
extern "C" void kernel_launch(void* const* d_in, const int* in_sizes, int n_in,
                              void* d_out, int out_size, void* d_ws, size_t ws_size,
                              hipStream_t stream) {
  const float* q = (const float*)d_in[0];
  const float* k = (const float*)d_in[1];
  const float* v = (const float*)d_in[2];
  const float* mask = (const float*)d_in[3];
  const float* WQ = (const float*)d_in[4];
  const float* bQ = (const float*)d_in[5];
  const float* WK = (const float*)d_in[6];
  const float* bK = (const float*)d_in[7];
  const float* WV = (const float*)d_in[8];
  const float* bV = (const float*)d_in[9];
  const float* WO = (const float*)d_in[10];
  const float* bO = (const float*)d_in[11];

  _Float16* ws = (_Float16*)d_ws;
  const size_t MD = (size_t)Mn * Dn;   // 4.19M elems
  const size_t DD = (size_t)Dn * Dn;   // 1.05M
  _Float16* qh  = ws;
  _Float16* kh  = ws + MD;
  _Float16* vh  = ws + 2 * MD;
  _Float16* WQh = ws + 3 * MD;
  _Float16* WKh = WQh + DD;
  _Float16* WVh = WKh + DD;
  _Float16* WOh = WVh + DD;
  _Float16* Qh  = ws + 3 * MD + 4 * DD;
  _Float16* Kh  = Qh + MD;
  _Float16* Vt  = Kh + MD;
  _Float16* AO  = qh;  // qh dead after QKV gemm

  CvtJobs cj;
  cj.src[0] = q;  cj.dst[0] = qh;  cj.n4[0] = (int)(MD / 4);
  cj.src[1] = k;  cj.dst[1] = kh;  cj.n4[1] = (int)(MD / 4);
  cj.src[2] = v;  cj.dst[2] = vh;  cj.n4[2] = (int)(MD / 4);
  cj.src[3] = WQ; cj.dst[3] = WQh; cj.n4[3] = (int)(DD / 4);
  cj.src[4] = WK; cj.dst[4] = WKh; cj.n4[4] = (int)(DD / 4);
  cj.src[5] = WV; cj.dst[5] = WVh; cj.n4[5] = (int)(DD / 4);
  cj.src[6] = WO; cj.dst[6] = WOh; cj.n4[6] = (int)(DD / 4);
  cvt_kernel<<<1024, 256, 0, stream>>>(cj);

  QkvArgs ga;
  ga.X[0] = qh; ga.W[0] = WQh; ga.bias[0] = bQ; ga.out[0] = Qh;
  ga.X[1] = kh; ga.W[1] = WKh; ga.bias[1] = bK; ga.out[1] = Kh;
  ga.X[2] = vh; ga.W[2] = WVh; ga.bias[2] = bV; ga.out[2] = Vt;
  gemm_qkv<<<dim3(Nn / 128, Mn / 128, 3), 256, 0, stream>>>(ga);

  attn_kernel<<<dim3(Sn / 64, Bn * Hn), 256, 0, stream>>>(Qh, Kh, Vt, mask, AO);

  gemm_o<<<dim3(Nn / 128, Mn / 128), 256, 0, stream>>>(AO, WOh, bO, (float*)d_out);
}